// Round 8
// baseline (220.276 us; speedup 1.0000x reference)
//
#include <hip/hip_runtime.h>
#include <hip/hip_bf16.h>

#define S_TOK 8192
#define NEXP 64
#define MDIM 1024
#define CAP 128
#define BLK_TOK 32       // tokens per gate block
#define NCH 256          // S_TOK / BLK_TOK
#define NGATE 256
#define NFILL 2048
#define SLAB 16450       // float4 slots per fill block

// flat output element offsets (fp32)
#define OFF2 67108865    // dispatch_mask start  (1 + 8192*64*128)
#define OFF3 134217729   // mask1 start
#define OFF4 134742017   // exp_counts start
#define OFF5 134742081   // indices1_s start
#define OUT_ELEMS 134750273
#define SLOTS_TOT 33687568   // (OUT_ELEMS-1)/4, exact

// ---------------- Fused: 256 gate blocks (first, 1/CU, ~8.3 KB LDS, short)
// + 2048 contiguous-slab zero-fill blocks. Gate writes ws only; fill writes
// out only. Small LDS keeps fill residency at 8 blocks/CU (store streams
// saturate at ~3.5 waves/CU per the rocclr fill counters).
__global__ __launch_bounds__(256) void fused_kernel(
    const float* __restrict__ x, const float* __restrict__ wg,
    unsigned char* __restrict__ ind, unsigned char* __restrict__ rnk,
    float* __restrict__ gval, unsigned char* __restrict__ counts,
    float* __restrict__ gparts, float* __restrict__ out)
{
  __shared__ float g_all[BLK_TOK][NEXP];   // 8 KB
  __shared__ int s_ind[BLK_TOK];
  const int b = blockIdx.x;

  if (b >= NGATE) {
    // ---- fill path: one contiguous ~257 KB slab of zeros ----
    const long long start = (long long)(b - NGATE) * SLAB;
    long long end = start + SLAB;
    if (end > SLOTS_TOT) end = SLOTS_TOT;
    float4* o4 = reinterpret_cast<float4*>(out);
    const float4 z = make_float4(0.f, 0.f, 0.f, 0.f);
    for (long long j = start + threadIdx.x; j < end; j += 256) o4[j] = z;
    if (b == NGATE && threadIdx.x == 0) out[OUT_ELEMS - 1] = 0.f;
    return;
  }

  // ---- gate path: thread = 4 experts x 2 tokens, K=1024 straight from cache
  const int tid = threadIdx.x;
  const int lane = tid & 63;
  const int wv = tid >> 6;                 // wave 0..3 -> tokens 8wv..8wv+8
  const int eg = lane & 15;                // experts 4eg..4eg+3
  const int tg = lane >> 4;                // 0..3
  const int t0 = wv * 8 + tg;              // local tokens t0, t0+4
  const int gt0 = b * BLK_TOK + t0;

  const float4* x4 = reinterpret_cast<const float4*>(x);
  const float4* wg4 = reinterpret_cast<const float4*>(wg);
  const float4* xr0 = x4 + (size_t)gt0 * (MDIM / 4);
  const float4* xr1 = xr0 + (size_t)4 * (MDIM / 4);

  float4 a0 = make_float4(0.f, 0.f, 0.f, 0.f);
  float4 a1 = make_float4(0.f, 0.f, 0.f, 0.f);
#pragma unroll 4
  for (int dq = 0; dq < MDIM / 4; ++dq) {
    const float4 w0 = wg4[(4 * dq + 0) * 16 + eg];
    const float4 w1 = wg4[(4 * dq + 1) * 16 + eg];
    const float4 w2 = wg4[(4 * dq + 2) * 16 + eg];
    const float4 w3 = wg4[(4 * dq + 3) * 16 + eg];
    const float4 xv0 = xr0[dq];
    const float4 xv1 = xr1[dq];
    a0.x = fmaf(xv0.x, w0.x, fmaf(xv0.y, w1.x, fmaf(xv0.z, w2.x, fmaf(xv0.w, w3.x, a0.x))));
    a0.y = fmaf(xv0.x, w0.y, fmaf(xv0.y, w1.y, fmaf(xv0.z, w2.y, fmaf(xv0.w, w3.y, a0.y))));
    a0.z = fmaf(xv0.x, w0.z, fmaf(xv0.y, w1.z, fmaf(xv0.z, w2.z, fmaf(xv0.w, w3.z, a0.z))));
    a0.w = fmaf(xv0.x, w0.w, fmaf(xv0.y, w1.w, fmaf(xv0.z, w2.w, fmaf(xv0.w, w3.w, a0.w))));
    a1.x = fmaf(xv1.x, w0.x, fmaf(xv1.y, w1.x, fmaf(xv1.z, w2.x, fmaf(xv1.w, w3.x, a1.x))));
    a1.y = fmaf(xv1.x, w0.y, fmaf(xv1.y, w1.y, fmaf(xv1.z, w2.y, fmaf(xv1.w, w3.y, a1.y))));
    a1.z = fmaf(xv1.x, w0.z, fmaf(xv1.y, w1.z, fmaf(xv1.z, w2.z, fmaf(xv1.w, w3.z, a1.z))));
    a1.w = fmaf(xv1.x, w0.w, fmaf(xv1.y, w1.w, fmaf(xv1.z, w2.w, fmaf(xv1.w, w3.w, a1.w))));
  }

  // per-token softmax/argmax over 64 experts (16 eg lanes hold them)
#pragma unroll
  for (int half = 0; half < 2; ++half) {
    const float4 lg = half ? a1 : a0;
    const int tl = t0 + half * 4;
    float m = lg.x; int ei = eg * 4;       // lowest index wins ties
    if (lg.y > m) { m = lg.y; ei = eg * 4 + 1; }
    if (lg.z > m) { m = lg.z; ei = eg * 4 + 2; }
    if (lg.w > m) { m = lg.w; ei = eg * 4 + 3; }
#pragma unroll
    for (int off = 1; off <= 8; off <<= 1) {
      const float om = __shfl_xor(m, off, 64);
      const int oe = __shfl_xor(ei, off, 64);
      if (om > m || (om == m && oe < ei)) { m = om; ei = oe; }
    }
    const float e0 = __expf(lg.x - m), e1 = __expf(lg.y - m),
                e2 = __expf(lg.z - m), e3 = __expf(lg.w - m);
    float sm = e0 + e1 + e2 + e3;
#pragma unroll
    for (int off = 1; off <= 8; off <<= 1) sm += __shfl_xor(sm, off, 64);
    const float inv = 1.0f / sm;
    *reinterpret_cast<float4*>(&g_all[tl][eg * 4]) =
        make_float4(e0 * inv, e1 * inv, e2 * inv, e3 * inv);
    if (eg == 0) {
      s_ind[tl] = ei;
      const int gt = b * BLK_TOK + tl;
      ind[gt] = (unsigned char)ei;
      gval[gt] = inv;                      // winner gate = exp(0)/sum
    }
  }
  __syncthreads();

  if (wv == 0) {                           // lane = expert
    float colsum = 0.f;
#pragma unroll
    for (int t = 0; t < BLK_TOK; ++t) colsum += g_all[t][lane];
    gparts[b * NEXP + lane] = colsum;
    int cnt = 0;                           // deterministic within-chunk rank
#pragma unroll
    for (int t = 0; t < BLK_TOK; ++t) {
      const int e = s_ind[t];
      const int r = __shfl(cnt, e, 64);
      if (lane == 0) rnk[b * BLK_TOK + t] = (unsigned char)r;
      cnt += (lane == e) ? 1 : 0;
    }
    counts[b * NEXP + lane] = (unsigned char)cnt;
  }
}

// ---------------- Reduce: per-expert prefix over 256 chunks (16 groups x 16)
__global__ __launch_bounds__(1024) void reduce_kernel(
    const unsigned char* __restrict__ counts, const float* __restrict__ gparts,
    unsigned short* __restrict__ offs, float* __restrict__ out)
{
  __shared__ int s_cnt[16][64];
  __shared__ float s_gs[16][64];
  const int e = threadIdx.x & 63;
  const int g = threadIdx.x >> 6;          // group 0..15, 16 chunks each
  const int ch0 = g * 16;

  int csum = 0; float gsum = 0.f;
#pragma unroll
  for (int ch = ch0; ch < ch0 + 16; ++ch) {
    csum += (int)counts[ch * NEXP + e];
    gsum += gparts[ch * NEXP + e];
  }
  s_cnt[g][e] = csum; s_gs[g][e] = gsum;
  __syncthreads();

  int base = 0;
  for (int k = 0; k < g; ++k) base += s_cnt[k][e];
  int run = base;
#pragma unroll
  for (int ch = ch0; ch < ch0 + 16; ++ch) {
    offs[ch * NEXP + e] = (unsigned short)run;   // exclusive per-expert prefix
    run += (int)counts[ch * NEXP + e];
  }
  if (g == 15) {
    const int total = run;
    out[OFF4 + e] = (float)total;
    float gtot = 0.f;
#pragma unroll
    for (int k = 0; k < 16; ++k) gtot += s_gs[k][e];
    const float me = gtot * (1.0f / (float)S_TOK);
    const float ce = (float)total * (1.0f / (float)S_TOK);
    float prod = me * ce;
#pragma unroll
    for (int off = 32; off > 0; off >>= 1) prod += __shfl_xor(prod, off, 64);
    if (e == 0) out[0] = prod * (float)NEXP;     // l_aux
  }
}

// ---------------- Scatter: nonzeros into the zeroed field
__global__ __launch_bounds__(256) void scatter_kernel(
    const unsigned char* __restrict__ ind, const unsigned char* __restrict__ rnk,
    const unsigned short* __restrict__ offs, const float* __restrict__ gval,
    float* __restrict__ out)
{
  const int s = blockIdx.x * 256 + threadIdx.x;
  if (s >= S_TOK) return;
  const int e = (int)ind[s];
  const int loc = (int)offs[(s >> 5) * NEXP + e] + (int)rnk[s];
  out[OFF5 + s] = (float)e;                      // indices1_s
  out[OFF3 + (s << 6) + e] = 1.0f;               // mask1
  if (loc < CAP) {
    const int rel = (s << 13) + (e << 7) + loc;  // s*8192 + e*128 + loc
    out[1 + rel] = gval[s];                      // combine_weights
    out[OFF2 + rel] = 1.0f;                      // dispatch_mask
  }
}

extern "C" void kernel_launch(void* const* d_in, const int* in_sizes, int n_in,
                              void* d_out, int out_size, void* d_ws, size_t ws_size,
                              hipStream_t stream)
{
  const float* x = (const float*)d_in[0];
  const float* wg = (const float*)d_in[1];
  float* out = (float*)d_out;

  // ws layout (~152 KB)
  float* gval = (float*)d_ws;                                     // 8192 f32
  float* gparts = gval + S_TOK;                                   // 256*64 f32
  unsigned short* offs = (unsigned short*)(gparts + NCH * NEXP);  // 256*64 u16
  unsigned char* ind = (unsigned char*)(offs + NCH * NEXP);       // 8192 u8
  unsigned char* rnk = ind + S_TOK;                               // 8192 u8
  unsigned char* counts = rnk + S_TOK;                            // 256*64 u8

  fused_kernel<<<NGATE + NFILL, 256, 0, stream>>>(x, wg, ind, rnk, gval, counts, gparts, out);
  reduce_kernel<<<1, 1024, 0, stream>>>(counts, gparts, offs, out);
  scatter_kernel<<<(S_TOK + 255) / 256, 256, 0, stream>>>(ind, rnk, offs, gval, out);
}

// Round 10
// 168.929 us; speedup vs baseline: 1.3040x; 1.3040x over previous
//
#include <hip/hip_runtime.h>
#include <hip/hip_bf16.h>

#define S_TOK 8192
#define NEXP 64
#define MDIM 1024
#define CAP 128
#define BLK_TOK 32       // tokens per gate block
#define NCH 256          // S_TOK / BLK_TOK

// flat output element offsets (fp32)
#define OFF2 67108865    // dispatch_mask start  (1 + 8192*64*128)
#define OFF3 134217729   // mask1 start
#define OFF4 134742017   // exp_counts start
#define OFF5 134742081   // indices1_s start
#define OUT_ELEMS 134750273
#define SLOTS_TOT 33687568   // (OUT_ELEMS-1)/4, exact
#define NFILL 2048
#define SLAB 16450           // float4 slots per fill block (2048*16450 >= SLOTS_TOT)

typedef float floatx4 __attribute__((ext_vector_type(4)));  // native vector for nt-store

// ---------------- Fill: contiguous slabs, nontemporal 16B stores.
__global__ __launch_bounds__(256) void fill_kernel(float* __restrict__ out)
{
  const long long start = (long long)blockIdx.x * SLAB;
  long long end = start + SLAB;
  if (end > SLOTS_TOT) end = SLOTS_TOT;
  floatx4* o4 = reinterpret_cast<floatx4*>(out);
  const floatx4 z = {0.f, 0.f, 0.f, 0.f};
#pragma unroll 4
  for (long long j = start + threadIdx.x; j < end; j += 256)
    __builtin_nontemporal_store(z, o4 + j);
  if (blockIdx.x == 0 && threadIdx.x == 0) out[OUT_ELEMS - 1] = 0.f;
}

// ---------------- Gate (R7, verified): K split across 4 waves; thread = 4 exp x 8 tok.
__global__ __launch_bounds__(256) void gate_kernel(
    const float* __restrict__ x, const float* __restrict__ wg,
    unsigned char* __restrict__ ind, unsigned char* __restrict__ rnk,
    float* __restrict__ gval, unsigned char* __restrict__ counts,
    float* __restrict__ gparts)
{
  __shared__ float wgt[4 * 64 * NEXP];     // 64 KB: [wave][64 rows][64 exp]; reused for partials
  __shared__ float g_all[BLK_TOK][NEXP];   // 8 KB gates (for l_aux colsums)
  __shared__ int s_ind[BLK_TOK];
  const int b = blockIdx.x;
  const int tid = threadIdx.x;
  const int lane = tid & 63;
  const int wv = tid >> 6;                 // wave 0..3 = K-quarter
  const int eg = lane & 15;                // experts 4eg..4eg+3
  const int tg = lane >> 4;                // token octet 0..3
  const int tokbase = b * BLK_TOK + tg * 8;

  const float4* x4 = reinterpret_cast<const float4*>(x);
  const float4* wg4 = reinterpret_cast<const float4*>(wg);
  float4* wgt4 = reinterpret_cast<float4*>(wgt);

  float4 acc[8];
#pragma unroll
  for (int j = 0; j < 8; ++j) acc[j] = make_float4(0.f, 0.f, 0.f, 0.f);

#pragma unroll
  for (int p = 0; p < 4; ++p) {
    __syncthreads();                       // prior phase fully consumed
#pragma unroll
    for (int k = 0; k < 16; ++k) {
      const int c = k * 256 + tid;         // 0..4095 float4
      const int wq = c >> 10;
      const int rem = c & 1023;            // r*16 + e4
      wgt4[c] = wg4[wq * 4096 + p * 1024 + rem];
    }
    __syncthreads();

    const float4* wrow = wgt4 + wv * 1024; // this wave's 64-row slice
    const int xcol0 = wv * 64 + p * 16;    // float4 column base into x row
#pragma unroll 2
    for (int dq = 0; dq < 16; ++dq) {
      const float4 w0 = wrow[(4 * dq + 0) * 16 + eg];
      const float4 w1 = wrow[(4 * dq + 1) * 16 + eg];
      const float4 w2 = wrow[(4 * dq + 2) * 16 + eg];
      const float4 w3 = wrow[(4 * dq + 3) * 16 + eg];
#pragma unroll
      for (int j = 0; j < 8; ++j) {
        const float4 xv = x4[(tokbase + j) * (MDIM / 4) + xcol0 + dq];
        acc[j].x = fmaf(xv.x, w0.x, fmaf(xv.y, w1.x, fmaf(xv.z, w2.x, fmaf(xv.w, w3.x, acc[j].x))));
        acc[j].y = fmaf(xv.x, w0.y, fmaf(xv.y, w1.y, fmaf(xv.z, w2.y, fmaf(xv.w, w3.y, acc[j].y))));
        acc[j].z = fmaf(xv.x, w0.z, fmaf(xv.y, w1.z, fmaf(xv.z, w2.z, fmaf(xv.w, w3.z, acc[j].z))));
        acc[j].w = fmaf(xv.x, w0.w, fmaf(xv.y, w1.w, fmaf(xv.z, w2.w, fmaf(xv.w, w3.w, acc[j].w))));
      }
    }
  }

  // ---- cross-wave reduction of K-partials (reuse wgt as [wv][tok][16 f4])
  __syncthreads();
#pragma unroll
  for (int j = 0; j < 8; ++j)
    wgt4[(wv * BLK_TOK + tg * 8 + j) * 16 + eg] = acc[j];
  __syncthreads();

  // ---- softmax + argmax: wave wv handles tokens [8wv, 8wv+8), 4 per pass
#pragma unroll
  for (int jj = 0; jj < 2; ++jj) {
    const int tl = wv * 8 + jj * 4 + tg;   // local token
    const float4 s0 = wgt4[(0 * BLK_TOK + tl) * 16 + eg];
    const float4 s1 = wgt4[(1 * BLK_TOK + tl) * 16 + eg];
    const float4 s2 = wgt4[(2 * BLK_TOK + tl) * 16 + eg];
    const float4 s3 = wgt4[(3 * BLK_TOK + tl) * 16 + eg];
    const float l0 = s0.x + s1.x + s2.x + s3.x;
    const float l1 = s0.y + s1.y + s2.y + s3.y;
    const float l2 = s0.z + s1.z + s2.z + s3.z;
    const float l3 = s0.w + s1.w + s2.w + s3.w;

    float m = l0; int ei = eg * 4;         // lowest index wins ties (strict >)
    if (l1 > m) { m = l1; ei = eg * 4 + 1; }
    if (l2 > m) { m = l2; ei = eg * 4 + 2; }
    if (l3 > m) { m = l3; ei = eg * 4 + 3; }
#pragma unroll
    for (int off = 1; off <= 8; off <<= 1) {
      const float om = __shfl_xor(m, off, 64);
      const int oe = __shfl_xor(ei, off, 64);
      if (om > m || (om == m && oe < ei)) { m = om; ei = oe; }
    }
    const float e0 = __expf(l0 - m), e1 = __expf(l1 - m),
                e2 = __expf(l2 - m), e3 = __expf(l3 - m);
    float sm = e0 + e1 + e2 + e3;
#pragma unroll
    for (int off = 1; off <= 8; off <<= 1) sm += __shfl_xor(sm, off, 64);
    const float inv = 1.0f / sm;

    *reinterpret_cast<float4*>(&g_all[tl][eg * 4]) =
        make_float4(e0 * inv, e1 * inv, e2 * inv, e3 * inv);
    if (eg == 0) {
      s_ind[tl] = ei;
      const int gt = b * BLK_TOK + tl;
      ind[gt] = (unsigned char)ei;
      gval[gt] = inv;                      // winner gate = exp(0)/sum
    }
  }
  __syncthreads();

  if (wv == 0) {                           // lane = expert
    float colsum = 0.f;
#pragma unroll
    for (int t = 0; t < BLK_TOK; ++t) colsum += g_all[t][lane];
    gparts[b * NEXP + lane] = colsum;
    int cnt = 0;                           // deterministic within-chunk rank
#pragma unroll
    for (int t = 0; t < BLK_TOK; ++t) {
      const int e = s_ind[t];
      const int r = __shfl(cnt, e, 64);
      if (lane == 0) rnk[b * BLK_TOK + t] = (unsigned char)r;
      cnt += (lane == e) ? 1 : 0;
    }
    counts[b * NEXP + lane] = (unsigned char)cnt;
  }
}

// ---------------- Reduce: per-expert prefix over 256 chunks (16 groups x 16)
__global__ __launch_bounds__(1024) void reduce_kernel(
    const unsigned char* __restrict__ counts, const float* __restrict__ gparts,
    unsigned short* __restrict__ offs, float* __restrict__ out)
{
  __shared__ int s_cnt[16][64];
  __shared__ float s_gs[16][64];
  const int e = threadIdx.x & 63;
  const int g = threadIdx.x >> 6;          // group 0..15, 16 chunks each
  const int ch0 = g * 16;

  int csum = 0; float gsum = 0.f;
#pragma unroll
  for (int ch = ch0; ch < ch0 + 16; ++ch) {
    csum += (int)counts[ch * NEXP + e];
    gsum += gparts[ch * NEXP + e];
  }
  s_cnt[g][e] = csum; s_gs[g][e] = gsum;
  __syncthreads();

  int base = 0;
  for (int k = 0; k < g; ++k) base += s_cnt[k][e];
  int run = base;
#pragma unroll
  for (int ch = ch0; ch < ch0 + 16; ++ch) {
    offs[ch * NEXP + e] = (unsigned short)run;   // exclusive per-expert prefix
    run += (int)counts[ch * NEXP + e];
  }
  if (g == 15) {
    const int total = run;
    out[OFF4 + e] = (float)total;
    float gtot = 0.f;
#pragma unroll
    for (int k = 0; k < 16; ++k) gtot += s_gs[k][e];
    const float me = gtot * (1.0f / (float)S_TOK);
    const float ce = (float)total * (1.0f / (float)S_TOK);
    float prod = me * ce;
#pragma unroll
    for (int off = 32; off > 0; off >>= 1) prod += __shfl_xor(prod, off, 64);
    if (e == 0) out[0] = prod * (float)NEXP;     // l_aux
  }
}

// ---------------- Scatter: nonzeros into the zeroed field
__global__ __launch_bounds__(256) void scatter_kernel(
    const unsigned char* __restrict__ ind, const unsigned char* __restrict__ rnk,
    const unsigned short* __restrict__ offs, const float* __restrict__ gval,
    float* __restrict__ out)
{
  const int s = blockIdx.x * 256 + threadIdx.x;
  if (s >= S_TOK) return;
  const int e = (int)ind[s];
  const int loc = (int)offs[(s >> 5) * NEXP + e] + (int)rnk[s];
  out[OFF5 + s] = (float)e;                      // indices1_s
  out[OFF3 + (s << 6) + e] = 1.0f;               // mask1
  if (loc < CAP) {
    const int rel = (s << 13) + (e << 7) + loc;  // s*8192 + e*128 + loc
    out[1 + rel] = gval[s];                      // combine_weights
    out[OFF2 + rel] = 1.0f;                      // dispatch_mask
  }
}

extern "C" void kernel_launch(void* const* d_in, const int* in_sizes, int n_in,
                              void* d_out, int out_size, void* d_ws, size_t ws_size,
                              hipStream_t stream)
{
  const float* x = (const float*)d_in[0];
  const float* wg = (const float*)d_in[1];
  float* out = (float*)d_out;

  // ws layout (~152 KB)
  float* gval = (float*)d_ws;                                     // 8192 f32
  float* gparts = gval + S_TOK;                                   // 256*64 f32
  unsigned short* offs = (unsigned short*)(gparts + NCH * NEXP);  // 256*64 u16
  unsigned char* ind = (unsigned char*)(offs + NCH * NEXP);       // 8192 u8
  unsigned char* rnk = ind + S_TOK;                               // 8192 u8
  unsigned char* counts = rnk + S_TOK;                            // 256*64 u8

  fill_kernel<<<NFILL, 256, 0, stream>>>(out);
  gate_kernel<<<NCH, 256, 0, stream>>>(x, wg, ind, rnk, gval, counts, gparts);
  reduce_kernel<<<1, 1024, 0, stream>>>(counts, gparts, offs, out);
  scatter_kernel<<<(S_TOK + 255) / 256, 256, 0, stream>>>(ind, rnk, offs, gval, out);
}

// Round 11
// 130.510 us; speedup vs baseline: 1.6878x; 1.2944x over previous
//
#include <hip/hip_runtime.h>
#include <hip/hip_bf16.h>

#define S_TOK 8192
#define NEXP 64
#define MDIM 1024
#define CAP 128
#define BLK_TOK 16       // tokens per gate block (2 blocks/CU for latency hiding)
#define NCH 512          // S_TOK / BLK_TOK

// flat output element offsets (fp32)
#define OFF2 67108865    // dispatch_mask start  (1 + 8192*64*128)
#define OFF3 134217729   // mask1 start
#define OFF4 134742017   // exp_counts start
#define OFF5 134742081   // indices1_s start

// ---------------- Gate: K split across 4 waves (256 rows each); thread = 4 exp x 4 tok.
// 512 blocks, 68.3 KB LDS -> 2 blocks/CU = 2 waves/SIMD (staging overlaps compute).
__global__ __launch_bounds__(256, 2) void gate_kernel(
    const float* __restrict__ x, const float* __restrict__ wg,
    unsigned char* __restrict__ ind, unsigned char* __restrict__ rnk,
    float* __restrict__ gval, unsigned char* __restrict__ counts,
    float* __restrict__ gparts)
{
  __shared__ float wgt[4 * 64 * NEXP];     // 64 KB: [wave][64 rows][64 exp]; reused for partials
  __shared__ float g_all[BLK_TOK][NEXP];   // 4 KB gates (for l_aux colsums)
  __shared__ int s_ind[BLK_TOK];
  const int b = blockIdx.x;
  const int tid = threadIdx.x;
  const int lane = tid & 63;
  const int wv = tid >> 6;                 // wave 0..3 = K-quarter
  const int eg = lane & 15;                // experts 4eg..4eg+3
  const int tg = lane >> 4;                // token quartet 0..3
  const int tokbase = b * BLK_TOK + tg * 4;

  const float4* x4 = reinterpret_cast<const float4*>(x);
  const float4* wg4 = reinterpret_cast<const float4*>(wg);
  float4* wgt4 = reinterpret_cast<float4*>(wgt);

  float4 acc[4];
#pragma unroll
  for (int j = 0; j < 4; ++j) acc[j] = make_float4(0.f, 0.f, 0.f, 0.f);

#pragma unroll
  for (int p = 0; p < 4; ++p) {
    __syncthreads();                       // prior phase fully consumed
#pragma unroll
    for (int k = 0; k < 16; ++k) {
      const int c = k * 256 + tid;         // 0..4095 float4
      const int wq = c >> 10;
      const int rem = c & 1023;            // r*16 + e4
      wgt4[c] = wg4[wq * 4096 + p * 1024 + rem];
    }
    __syncthreads();

    const float4* wrow = wgt4 + wv * 1024; // this wave's 64-row slice
    const int xcol0 = wv * 64 + p * 16;    // float4 column base into x row
#pragma unroll 2
    for (int dq = 0; dq < 16; ++dq) {
      const float4 w0 = wrow[(4 * dq + 0) * 16 + eg];
      const float4 w1 = wrow[(4 * dq + 1) * 16 + eg];
      const float4 w2 = wrow[(4 * dq + 2) * 16 + eg];
      const float4 w3 = wrow[(4 * dq + 3) * 16 + eg];
#pragma unroll
      for (int j = 0; j < 4; ++j) {
        const float4 xv = x4[(tokbase + j) * (MDIM / 4) + xcol0 + dq];
        acc[j].x = fmaf(xv.x, w0.x, fmaf(xv.y, w1.x, fmaf(xv.z, w2.x, fmaf(xv.w, w3.x, acc[j].x))));
        acc[j].y = fmaf(xv.x, w0.y, fmaf(xv.y, w1.y, fmaf(xv.z, w2.y, fmaf(xv.w, w3.y, acc[j].y))));
        acc[j].z = fmaf(xv.x, w0.z, fmaf(xv.y, w1.z, fmaf(xv.z, w2.z, fmaf(xv.w, w3.z, acc[j].z))));
        acc[j].w = fmaf(xv.x, w0.w, fmaf(xv.y, w1.w, fmaf(xv.z, w2.w, fmaf(xv.w, w3.w, acc[j].w))));
      }
    }
  }

  // ---- cross-wave reduction of K-partials (reuse wgt as [wv][tok][16 f4])
  __syncthreads();
#pragma unroll
  for (int j = 0; j < 4; ++j)
    wgt4[(wv * BLK_TOK + tg * 4 + j) * 16 + eg] = acc[j];
  __syncthreads();

  // ---- softmax + argmax: wave wv handles tokens [4wv, 4wv+4), one per tg
  {
    const int tl = wv * 4 + tg;            // local token
    const float4 s0 = wgt4[(0 * BLK_TOK + tl) * 16 + eg];
    const float4 s1 = wgt4[(1 * BLK_TOK + tl) * 16 + eg];
    const float4 s2 = wgt4[(2 * BLK_TOK + tl) * 16 + eg];
    const float4 s3 = wgt4[(3 * BLK_TOK + tl) * 16 + eg];
    const float l0 = s0.x + s1.x + s2.x + s3.x;
    const float l1 = s0.y + s1.y + s2.y + s3.y;
    const float l2 = s0.z + s1.z + s2.z + s3.z;
    const float l3 = s0.w + s1.w + s2.w + s3.w;

    float m = l0; int ei = eg * 4;         // lowest index wins ties (strict >)
    if (l1 > m) { m = l1; ei = eg * 4 + 1; }
    if (l2 > m) { m = l2; ei = eg * 4 + 2; }
    if (l3 > m) { m = l3; ei = eg * 4 + 3; }
#pragma unroll
    for (int off = 1; off <= 8; off <<= 1) {
      const float om = __shfl_xor(m, off, 64);
      const int oe = __shfl_xor(ei, off, 64);
      if (om > m || (om == m && oe < ei)) { m = om; ei = oe; }
    }
    const float e0 = __expf(l0 - m), e1 = __expf(l1 - m),
                e2 = __expf(l2 - m), e3 = __expf(l3 - m);
    float sm = e0 + e1 + e2 + e3;
#pragma unroll
    for (int off = 1; off <= 8; off <<= 1) sm += __shfl_xor(sm, off, 64);
    const float inv = 1.0f / sm;

    *reinterpret_cast<float4*>(&g_all[tl][eg * 4]) =
        make_float4(e0 * inv, e1 * inv, e2 * inv, e3 * inv);
    if (eg == 0) {
      s_ind[tl] = ei;
      const int gt = b * BLK_TOK + tl;
      ind[gt] = (unsigned char)ei;
      gval[gt] = inv;                      // winner gate = exp(0)/sum
    }
  }
  __syncthreads();

  if (wv == 0) {                           // lane = expert
    float colsum = 0.f;
#pragma unroll
    for (int t = 0; t < BLK_TOK; ++t) colsum += g_all[t][lane];
    gparts[b * NEXP + lane] = colsum;
    int cnt = 0;                           // deterministic within-chunk rank
#pragma unroll
    for (int t = 0; t < BLK_TOK; ++t) {
      const int e = s_ind[t];
      const int r = __shfl(cnt, e, 64);
      if (lane == 0) rnk[b * BLK_TOK + t] = (unsigned char)r;
      cnt += (lane == e) ? 1 : 0;
    }
    counts[b * NEXP + lane] = (unsigned char)cnt;
  }
}

// ---------------- Reduce: per-expert prefix over 512 chunks (16 groups x 32)
__global__ __launch_bounds__(1024) void reduce_kernel(
    const unsigned char* __restrict__ counts, const float* __restrict__ gparts,
    unsigned short* __restrict__ offs, float* __restrict__ out)
{
  __shared__ int s_cnt[16][64];
  __shared__ float s_gs[16][64];
  const int e = threadIdx.x & 63;
  const int g = threadIdx.x >> 6;          // group 0..15, 32 chunks each
  const int ch0 = g * 32;

  int csum = 0; float gsum = 0.f;
#pragma unroll
  for (int ch = ch0; ch < ch0 + 32; ++ch) {
    csum += (int)counts[ch * NEXP + e];
    gsum += gparts[ch * NEXP + e];
  }
  s_cnt[g][e] = csum; s_gs[g][e] = gsum;
  __syncthreads();

  int base = 0;
  for (int k = 0; k < g; ++k) base += s_cnt[k][e];
  int run = base;
#pragma unroll
  for (int ch = ch0; ch < ch0 + 32; ++ch) {
    offs[ch * NEXP + e] = (unsigned short)run;   // exclusive per-expert prefix
    run += (int)counts[ch * NEXP + e];
  }
  if (g == 15) {
    const int total = run;
    out[OFF4 + e] = (float)total;
    float gtot = 0.f;
#pragma unroll
    for (int k = 0; k < 16; ++k) gtot += s_gs[k][e];
    const float me = gtot * (1.0f / (float)S_TOK);
    const float ce = (float)total * (1.0f / (float)S_TOK);
    float prod = me * ce;
#pragma unroll
    for (int off = 32; off > 0; off >>= 1) prod += __shfl_xor(prod, off, 64);
    if (e == 0) out[0] = prod * (float)NEXP;     // l_aux
  }
}

// ---------------- Scatter: nonzeros into the memset-zeroed field
__global__ __launch_bounds__(256) void scatter_kernel(
    const unsigned char* __restrict__ ind, const unsigned char* __restrict__ rnk,
    const unsigned short* __restrict__ offs, const float* __restrict__ gval,
    float* __restrict__ out)
{
  const int s = blockIdx.x * 256 + threadIdx.x;
  if (s >= S_TOK) return;
  const int e = (int)ind[s];
  const int loc = (int)offs[(s >> 4) * NEXP + e] + (int)rnk[s];
  out[OFF5 + s] = (float)e;                      // indices1_s
  out[OFF3 + (s << 6) + e] = 1.0f;               // mask1
  if (loc < CAP) {
    const int rel = (s << 13) + (e << 7) + loc;  // s*8192 + e*128 + loc
    out[1 + rel] = gval[s];                      // combine_weights
    out[OFF2 + rel] = 1.0f;                      // dispatch_mask
  }
}

extern "C" void kernel_launch(void* const* d_in, const int* in_sizes, int n_in,
                              void* d_out, int out_size, void* d_ws, size_t ws_size,
                              hipStream_t stream)
{
  const float* x = (const float*)d_in[0];
  const float* wg = (const float*)d_in[1];
  float* out = (float*)d_out;

  // ws layout (~272 KB)
  float* gval = (float*)d_ws;                                     // 8192 f32
  float* gparts = gval + S_TOK;                                   // 512*64 f32
  unsigned short* offs = (unsigned short*)(gparts + NCH * NEXP);  // 512*64 u16
  unsigned char* ind = (unsigned char*)(offs + NCH * NEXP);       // 8192 u8
  unsigned char* rnk = ind + S_TOK;                               // 8192 u8
  unsigned char* counts = rnk + S_TOK;                            // 512*64 u8

  hipMemsetAsync(out, 0, (size_t)out_size * sizeof(float), stream);
  gate_kernel<<<NCH, 256, 0, stream>>>(x, wg, ind, rnk, gval, counts, gparts);
  reduce_kernel<<<1, 1024, 0, stream>>>(counts, gparts, offs, out);
  scatter_kernel<<<(S_TOK + 255) / 256, 256, 0, stream>>>(ind, rnk, offs, gval, out);
}